// Round 6
// baseline (270.229 us; speedup 1.0000x reference)
//
#include <hip/hip_runtime.h>
#include <hip/hip_bf16.h>
#include <cstddef>
#include <cstdint>

// NonLocal block, MI355X. Round 4 kernel (2nd resubmit after GPU-acquisition
// timeouts): break the grid-limited occupancy wall. kA/kB split their
// reduction loops into 4 chunks (2048 blocks, fp32 partial accumulators +
// tiny reduce kernels); k4 splits output channels across waves.

namespace {
constexpr int kBt  = 8;
constexpr int kC   = 256;
constexpr int kCi  = 32;
constexpr int kN   = 4096;           // H*W
constexpr int kRowsT = kBt * kN;     // 32768
constexpr int kMCH = 4;              // m-chunks in kA
constexpr int kNCH = 4;              // n-chunks in kB
constexpr float kLog2e = 1.4426950408889634f;

typedef __attribute__((ext_vector_type(8))) short short8;
typedef __attribute__((ext_vector_type(4))) float f32x4;
}

__device__ __forceinline__ float fast_exp2(float x) { return __builtin_amdgcn_exp2f(x); }
__device__ __forceinline__ float fast_rcp(float x)  { return __builtin_amdgcn_rcpf(x); }
__device__ __forceinline__ float silu(float t) {
    return t * fast_rcp(1.f + fast_exp2(-t * kLog2e));
}
__device__ __forceinline__ unsigned short f2bf(float f) {
    union { float f; uint32_t u; } v; v.f = f;
    return (unsigned short)((v.u + 0x7FFFu + ((v.u >> 16) & 1u)) >> 16);
}
__device__ __forceinline__ float bf2f(unsigned short u) {
    union { uint32_t u; float f; } v; v.u = ((uint32_t)u) << 16;
    return v.f;
}

// ---------------------------------------------------------------------------
// K0: pack weights into MFMA A-fragment order (scale folded in).
// ---------------------------------------------------------------------------
__global__ __launch_bounds__(64) void k0_pack(
    const float* __restrict__ w1, const float* __restrict__ s1,
    const float* __restrict__ w2, const float* __restrict__ s2,
    const float* __restrict__ w3, const float* __restrict__ s3,
    const float* __restrict__ w4, const float* __restrict__ s4,
    short8* __restrict__ wfA, short8* __restrict__ w4f)
{
    const int l = threadIdx.x;
    const int bid = blockIdx.x;
    short8 v;
    if (bid < 48) {
        int ot = bid >> 3, kt = bid & 7;
        int p  = ot >> 1;
        int ocp = (ot & 1) * 16 + (l & 15);
        int k0  = kt * 32 + (l >> 4) * 8;
        const float* wp = (p == 0) ? w1 : (p == 1) ? w2 : w3;
        const float* sp = (p == 0) ? s1 : (p == 1) ? s2 : s3;
        float s = sp[ocp];
        #pragma unroll
        for (int e = 0; e < 8; ++e)
            v[e] = (short)f2bf(wp[ocp * kC + k0 + e] * s);
        wfA[bid * 64 + l] = v;
    } else {
        int ot = bid - 48;
        int oc = ot * 16 + (l & 15);
        int k0 = (l >> 4) * 8;
        float s = s4[oc];
        #pragma unroll
        for (int e = 0; e < 8; ++e)
            v[e] = (short)f2bf(w4[oc * kCi + k0 + e] * s);
        w4f[ot * 64 + l] = v;
    }
}

// ---------------------------------------------------------------------------
// K1: projections via MFMA (unchanged from round 3).
// ---------------------------------------------------------------------------
__global__ __launch_bounds__(256) void k1_mfma(
    const float* __restrict__ x, const short8* __restrict__ wfA,
    const float* __restrict__ b1, const float* __restrict__ b2,
    const float* __restrict__ b3,
    unsigned short* __restrict__ y1t, unsigned short* __restrict__ y2t,
    unsigned short* __restrict__ y3t)
{
    const int l  = threadIdx.x & 63;
    const int w  = threadIdx.x >> 6;
    const int b  = blockIdx.x >> 6;
    const int n0 = (blockIdx.x & 63) * 64 + w * 16;
    const int px = l & 15, g = l >> 4;

    const float* xb = x + (size_t)b * kC * kN + n0 + px;

    f32x4 acc[6];
    #pragma unroll
    for (int ot = 0; ot < 6; ++ot) acc[ot] = (f32x4){0.f, 0.f, 0.f, 0.f};

    #pragma unroll
    for (int kt = 0; kt < 8; ++kt) {
        const float* xc = xb + (size_t)(kt * 32 + g * 8) * kN;
        float f[8];
        #pragma unroll
        for (int e = 0; e < 8; ++e) f[e] = xc[(size_t)e * kN];
        short8 Bf;
        #pragma unroll
        for (int e = 0; e < 8; ++e) Bf[e] = (short)f2bf(f[e]);
        #pragma unroll
        for (int ot = 0; ot < 6; ++ot)
            acc[ot] = __builtin_amdgcn_mfma_f32_16x16x32_bf16(
                wfA[(ot * 8 + kt) * 64 + l], Bf, acc[ot], 0, 0, 0);
    }

    const size_t rowbase = ((size_t)(b * kN) + n0 + px) * kCi;
    #pragma unroll
    for (int pp = 0; pp < 3; ++pp) {
        const float* bp = (pp == 0) ? b1 : (pp == 1) ? b2 : b3;
        unsigned short* yp = (pp == 0) ? y1t : (pp == 1) ? y2t : y3t;
        const float mul = (pp == 1) ? kLog2e : 1.0f;
        #pragma unroll
        for (int h = 0; h < 2; ++h) {
            int ot = pp * 2 + h;
            int oc0 = h * 16 + 4 * g;
            unsigned int wd[2];
            #pragma unroll
            for (int j2 = 0; j2 < 2; ++j2) {
                float v0 = silu(acc[ot][2 * j2]     + bp[oc0 + 2 * j2])     * mul;
                float v1 = silu(acc[ot][2 * j2 + 1] + bp[oc0 + 2 * j2 + 1]) * mul;
                wd[j2] = (unsigned)f2bf(v0) | ((unsigned)f2bf(v1) << 16);
            }
            *(uint2*)(yp + rowbase + oc0) = make_uint2(wd[0], wd[1]);
        }
    }
}

// ---------------------------------------------------------------------------
// KA: partial softmax denominators, m-chunked for occupancy.
// grid = (512, kMCH); psum[mch][b*kN + n].
// ---------------------------------------------------------------------------
__global__ __launch_bounds__(256) void kA_stats(
    const unsigned short* __restrict__ y1t, const unsigned short* __restrict__ y2t,
    float* __restrict__ psum)
{
    const int l   = threadIdx.x & 63;
    const int w   = __builtin_amdgcn_readfirstlane(threadIdx.x >> 6);
    const int b   = blockIdx.x >> 6;
    const int n0  = (blockIdx.x & 63) * 64;
    const int m0  = blockIdx.y * (kN / kMCH);
    const int r16 = l & 15, g = l >> 4;

    const short8 Af = *(const short8*)(
        y2t + ((size_t)(b * kN + n0 + w * 16 + r16) * kCi + g * 8));
    const unsigned short* y1b =
        y1t + ((size_t)b * kN + m0 + r16) * kCi + g * 8;

    float s0 = 0.f, s1 = 0.f, s2 = 0.f, s3 = 0.f;
    #pragma unroll 4
    for (int mt = 0; mt < kN / kMCH / 16; ++mt) {
        short8 Bf = *(const short8*)(y1b + (size_t)mt * 16 * kCi);
        f32x4 z = {0.f, 0.f, 0.f, 0.f};
        f32x4 S = __builtin_amdgcn_mfma_f32_16x16x32_bf16(Af, Bf, z, 0, 0, 0);
        s0 += fast_exp2(S[0]);
        s1 += fast_exp2(S[1]);
        s2 += fast_exp2(S[2]);
        s3 += fast_exp2(S[3]);
    }
    #pragma unroll
    for (int d = 1; d < 16; d <<= 1) {
        s0 += __shfl_xor(s0, d);
        s1 += __shfl_xor(s1, d);
        s2 += __shfl_xor(s2, d);
        s3 += __shfl_xor(s3, d);
    }
    if (r16 == 0) {
        float* dst = psum + (size_t)blockIdx.y * kRowsT + (size_t)b * kN
                   + n0 + w * 16 + 4 * g;
        dst[0] = s0; dst[1] = s1; dst[2] = s2; dst[3] = s3;
    }
}

// ---------------------------------------------------------------------------
// KA2: combine psum chunks -> rcp -> v3T[b][c][n] = y3[n][c]/sumexp[n].
// ---------------------------------------------------------------------------
__global__ __launch_bounds__(256) void kA2_v3(
    const float* __restrict__ psum, const unsigned short* __restrict__ y3t,
    unsigned short* __restrict__ v3T)
{
    const int b  = blockIdx.x >> 6;
    const int n0 = (blockIdx.x & 63) * 64;
    __shared__ float rsum[64];
    const int t = threadIdx.x;
    if (t < 64) {
        size_t idx = (size_t)b * kN + n0 + t;
        float s = psum[idx];
        #pragma unroll
        for (int ch = 1; ch < kMCH; ++ch) s += psum[(size_t)ch * kRowsT + idx];
        rsum[t] = fast_rcp(s);
    }
    __syncthreads();

    const int c = t >> 3, q = t & 7;
    float rin[8];
    #pragma unroll
    for (int u = 0; u < 8; ++u) rin[u] = rsum[q * 8 + u];
    unsigned int wds[4];
    #pragma unroll
    for (int u = 0; u < 4; ++u) {
        float a0 = bf2f(y3t[(size_t)(b * kN + n0 + q * 8 + 2 * u) * kCi + c]) * rin[2 * u];
        float a1 = bf2f(y3t[(size_t)(b * kN + n0 + q * 8 + 2 * u + 1) * kCi + c]) * rin[2 * u + 1];
        wds[u] = (unsigned)f2bf(a0) | ((unsigned)f2bf(a1) << 16);
    }
    *(uint4*)(v3T + ((size_t)(b * kCi + c) * kN + n0 + q * 8)) =
        make_uint4(wds[0], wds[1], wds[2], wds[3]);
}

// ---------------------------------------------------------------------------
// KB: PV pass, n-chunked. grid = (512, kNCH); fp32 partial acc.
// ---------------------------------------------------------------------------
__global__ __launch_bounds__(256) void kB_pv(
    const unsigned short* __restrict__ y1t, const unsigned short* __restrict__ y2t,
    const unsigned short* __restrict__ v3T, float* __restrict__ pacc)
{
    __shared__ unsigned int plds[4][20 * 16];   // per-wave P tile, 80B row stride
    const int l   = threadIdx.x & 63;
    const int w   = __builtin_amdgcn_readfirstlane(threadIdx.x >> 6);
    const int b   = blockIdx.x >> 6;
    const int m0  = (blockIdx.x & 63) * 64 + w * 16;
    const int n0c = blockIdx.y * (kN / kNCH);
    const int r16 = l & 15, g = l >> 4;

    const short8 B1 = *(const short8*)(
        y1t + ((size_t)(b * kN + m0 + r16) * kCi + g * 8));
    const unsigned short* y2b =
        y2t + ((size_t)b * kN + n0c + r16) * kCi + g * 8;
    const unsigned short* v3b =
        v3T + ((size_t)(b * kCi) + r16) * kN + n0c + g * 8;

    f32x4 acc0 = {0.f, 0.f, 0.f, 0.f};
    f32x4 acc1 = {0.f, 0.f, 0.f, 0.f};
    unsigned int* pw = &plds[w][r16 * 20];

    #pragma unroll 2
    for (int nt = 0; nt < kN / kNCH / 32; ++nt) {
        const size_t nb = (size_t)nt * 32;
        short8 A2a = *(const short8*)(y2b + nb * kCi);
        short8 A2b = *(const short8*)(y2b + (nb + 16) * kCi);
        f32x4 z = {0.f, 0.f, 0.f, 0.f};
        f32x4 S0 = __builtin_amdgcn_mfma_f32_16x16x32_bf16(A2a, B1, z, 0, 0, 0);
        f32x4 S1 = __builtin_amdgcn_mfma_f32_16x16x32_bf16(A2b, B1, z, 0, 0, 0);

        float p0 = fast_exp2(S0[0]), p1 = fast_exp2(S0[1]);
        float p2 = fast_exp2(S0[2]), p3 = fast_exp2(S0[3]);
        float p4 = fast_exp2(S1[0]), p5 = fast_exp2(S1[1]);
        float p6 = fast_exp2(S1[2]), p7 = fast_exp2(S1[3]);

        uint2 w01, w23;
        w01.x = (unsigned)f2bf(p0) | ((unsigned)f2bf(p1) << 16);
        w01.y = (unsigned)f2bf(p2) | ((unsigned)f2bf(p3) << 16);
        w23.x = (unsigned)f2bf(p4) | ((unsigned)f2bf(p5) << 16);
        w23.y = (unsigned)f2bf(p6) | ((unsigned)f2bf(p7) << 16);
        *(uint2*)(pw + 2 * g)     = w01;
        *(uint2*)(pw + 8 + 2 * g) = w23;

        short8 A3a = *(const short8*)(v3b + nb);
        short8 A3b = *(const short8*)(v3b + 16 * (size_t)kN + nb);

        asm volatile("" ::: "memory");
        short8 Bp = *(const short8*)(&plds[w][r16 * 20 + 4 * g]);

        acc0 = __builtin_amdgcn_mfma_f32_16x16x32_bf16(A3a, Bp, acc0, 0, 0, 0);
        acc1 = __builtin_amdgcn_mfma_f32_16x16x32_bf16(A3b, Bp, acc1, 0, 0, 0);
    }

    float* outp = pacc + ((size_t)blockIdx.y * kRowsT + (size_t)(b * kN) + m0 + r16) * kCi
                + 4 * g;
    *(float4*)(outp)      = make_float4(acc0[0], acc0[1], acc0[2], acc0[3]);
    *(float4*)(outp + 16) = make_float4(acc1[0], acc1[1], acc1[2], acc1[3]);
}

// ---------------------------------------------------------------------------
// KB2: sum the kNCH partial accumulators -> bf16 ylt rows.
// ---------------------------------------------------------------------------
__global__ __launch_bounds__(256) void kB2_reduce(
    const float* __restrict__ pacc, unsigned short* __restrict__ yltb)
{
    const size_t i = (size_t)blockIdx.x * 256 + threadIdx.x;   // float4 index
    const float4* src = reinterpret_cast<const float4*>(pacc);
    float4 s = src[i];
    #pragma unroll
    for (int ch = 1; ch < kNCH; ++ch) {
        float4 v = src[(size_t)ch * ((size_t)kRowsT * kCi / 4) + i];
        s.x += v.x; s.y += v.y; s.z += v.z; s.w += v.w;
    }
    uint2 o;
    o.x = (unsigned)f2bf(s.x) | ((unsigned)f2bf(s.y) << 16);
    o.y = (unsigned)f2bf(s.z) | ((unsigned)f2bf(s.w) << 16);
    *(uint2*)(yltb + 4 * i) = o;
}

// ---------------------------------------------------------------------------
// K4: final conv (32->256) + SiLU + residual. Wave = 16 px x 64 oc
// (4 waves split the 256 outputs) -> 2048 blocks, 8192 waves.
// ---------------------------------------------------------------------------
__global__ __launch_bounds__(256) void k4_mfma(
    const unsigned short* __restrict__ ylt, const short8* __restrict__ w4f,
    const float* __restrict__ b4, const float* __restrict__ x,
    float* __restrict__ out)
{
    const int l  = threadIdx.x & 63;
    const int w  = threadIdx.x >> 6;
    const int b  = blockIdx.x >> 8;
    const int n0 = (blockIdx.x & 255) * 16;
    const int px = l & 15, g = l >> 4;

    const short8 Bf = *(const short8*)(
        ylt + ((size_t)(b * kN) + n0 + px) * kCi + g * 8);

    f32x4 acc[4];
    #pragma unroll
    for (int u = 0; u < 4; ++u) {
        f32x4 z = {0.f, 0.f, 0.f, 0.f};
        acc[u] = __builtin_amdgcn_mfma_f32_16x16x32_bf16(
            w4f[(w * 4 + u) * 64 + l], Bf, z, 0, 0, 0);
    }

    const size_t pxg = (size_t)b * kC * kN + n0 + px;   // + oc*kN
    #pragma unroll
    for (int u = 0; u < 4; ++u) {
        const int oc0 = (w * 4 + u) * 16 + 4 * g;
        float4 bb = *(const float4*)(b4 + oc0);
        const float bbv[4] = {bb.x, bb.y, bb.z, bb.w};
        #pragma unroll
        for (int j = 0; j < 4; ++j) {
            const size_t idx = pxg + (size_t)(oc0 + j) * kN;
            float t = acc[u][j] + bbv[j];
            out[idx] = silu(t) + x[idx];
        }
    }
}

// ---------------------------------------------------------------------------
extern "C" void kernel_launch(void* const* d_in, const int* in_sizes, int n_in,
                              void* d_out, int out_size, void* d_ws, size_t ws_size,
                              hipStream_t stream)
{
    (void)in_sizes; (void)n_in; (void)out_size; (void)ws_size;
    const float* x  = (const float*)d_in[0];
    const float* w1 = (const float*)d_in[1];
    const float* s1 = (const float*)d_in[2];
    const float* b1 = (const float*)d_in[3];
    const float* w2 = (const float*)d_in[4];
    const float* s2 = (const float*)d_in[5];
    const float* b2 = (const float*)d_in[6];
    const float* w3 = (const float*)d_in[7];
    const float* s3 = (const float*)d_in[8];
    const float* b3 = (const float*)d_in[9];
    const float* w4 = (const float*)d_in[10];
    const float* s4 = (const float*)d_in[11];
    const float* b4 = (const float*)d_in[12];
    float* out = (float*)d_out;

    unsigned char* ws = (unsigned char*)d_ws;
    size_t off = 0;
    unsigned short* y1t = (unsigned short*)(ws + off); off += (size_t)kRowsT * kCi * 2;
    unsigned short* y2t = (unsigned short*)(ws + off); off += (size_t)kRowsT * kCi * 2;
    unsigned short* y3t = (unsigned short*)(ws + off); off += (size_t)kRowsT * kCi * 2;
    unsigned short* v3T = (unsigned short*)(ws + off); off += (size_t)kRowsT * kCi * 2;
    unsigned short* yltb= (unsigned short*)(ws + off); off += (size_t)kRowsT * kCi * 2;
    short8* wfA = (short8*)(ws + off); off += 48 * 64 * sizeof(short8);
    short8* w4f = (short8*)(ws + off); off += 16 * 64 * sizeof(short8);
    float* psum = (float*)(ws + off); off += (size_t)kMCH * kRowsT * 4;
    float* pacc = (float*)(ws + off); off += (size_t)kNCH * kRowsT * kCi * 4;

    k0_pack<<<dim3(64), dim3(64), 0, stream>>>(
        w1, s1, w2, s2, w3, s3, w4, s4, wfA, w4f);
    k1_mfma<<<dim3(kRowsT / 64), dim3(256), 0, stream>>>(
        x, wfA, b1, b2, b3, y1t, y2t, y3t);
    kA_stats<<<dim3(kBt * (kN / 64), kMCH), dim3(256), 0, stream>>>(
        y1t, y2t, psum);
    kA2_v3<<<dim3(kBt * (kN / 64)), dim3(256), 0, stream>>>(psum, y3t, v3T);
    kB_pv<<<dim3(kBt * (kN / 64), kNCH), dim3(256), 0, stream>>>(
        y1t, y2t, v3T, pacc);
    kB2_reduce<<<dim3((kRowsT * kCi / 4) / 256), dim3(256), 0, stream>>>(
        pacc, yltb);
    k4_mfma<<<dim3(kRowsT / 16), dim3(256), 0, stream>>>(
        yltb, w4f, b4, x, out);
}